// Round 1
// 383.203 us; speedup vs baseline: 1.0052x; 1.0052x over previous
//
#include <hip/hip_runtime.h>
#include <math.h>

#define M 16
#define KD 1024
#define CS_EPS 1e-6f

#define N0 (1024 * 1024)          // elements in rec0
#define N1 (1024 * 4096)          // elements in rec1
#define N40 (N0 / 4)              // float4 count, V0 slot  = 262144
#define N41 (N1 / 4)              // float4 count, V1 slot  = 1048576

typedef float vf4 __attribute__((ext_vector_type(4)));

__device__ __forceinline__ float sgpr_bcast(float x) {
    return __int_as_float(__builtin_amdgcn_readfirstlane(__float_as_int(x)));
}

// ---------------------------------------------------------------------------
// Fully fused kernel:
//   - each block recomputes w[16] from task_emb/K_memory (68 KB, L2-resident
//     after first touch -> ~free at HBM level); removes the separate
//     addr_head launch, its serial 1-block kernel, and all workspace use.
//   - slot-0 streaming loads are issued BEFORE the w-compute so the ~500cy
//     HBM latency of the first tile hides the whole prelude.
//   - streaming body unchanged from the 385us version: 4 vf4/thread,
//     block-strided, non-temporal loads/stores (read-once / write-once).
// ---------------------------------------------------------------------------
template<int PITCH4>
__device__ __forceinline__ void fused_body(
    const vf4* __restrict__ V,
    const float* __restrict__ task_emb,
    const float* __restrict__ K_memory,
    vf4* __restrict__ out,
    int blk)
{
    __shared__ float s_cos[M];

    const long long base = (long long)blk * 1024 + threadIdx.x;

    // ---- issue slot-0 loads first: independent of w ----
    const vf4* __restrict__ p0 = V + base;
    vf4 v0[4];
#pragma unroll
    for (int j = 0; j < 4; ++j) v0[j] = __builtin_nontemporal_load(p0 + j * 256);

    // ---- per-block w[16] recompute: 4 waves x 4 slots each ----
    const int lane = threadIdx.x & 63;
    const int wave = threadIdx.x >> 6;        // 0..3

    float t[KD / 64];
    float n1sq = 0.f;
#pragma unroll
    for (int k = 0; k < KD / 64; ++k) {
        t[k] = task_emb[lane + k * 64];
        n1sq += t[k] * t[k];
    }
#pragma unroll
    for (int off = 32; off; off >>= 1) n1sq += __shfl_down(n1sq, off, 64);
    const float n1 = sqrtf(__shfl(n1sq, 0, 64));

#pragma unroll
    for (int s = 0; s < 4; ++s) {
        const int slot = wave * 4 + s;
        float dot = 0.f, n2sq = 0.f;
#pragma unroll
        for (int k = 0; k < KD / 64; ++k) {
            float km = K_memory[slot * KD + lane + k * 64];
            dot  += t[k] * km;
            n2sq += km * km;
        }
#pragma unroll
        for (int off = 32; off; off >>= 1) {
            dot  += __shfl_down(dot,  off, 64);
            n2sq += __shfl_down(n2sq, off, 64);
        }
        if (lane == 0)
            s_cos[slot] = dot / fmaxf(n1 * sqrtf(n2sq), CS_EPS);
    }
    __syncthreads();

    // ---- softmax over 16 slots, redundantly per thread (broadcast LDS reads) ----
    float ws[M];
    {
        float c[M];
#pragma unroll
        for (int m = 0; m < M; ++m) c[m] = s_cos[m];
        float mx = -1e30f;
#pragma unroll
        for (int m = 0; m < M; ++m) mx = fmaxf(mx, c[m]);
        float sum = 0.f;
#pragma unroll
        for (int m = 0; m < M; ++m) { c[m] = expf(c[m] - mx); sum += c[m]; }
        const float inv = 1.f / sum;
#pragma unroll
        for (int m = 0; m < M; ++m) ws[m] = sgpr_bcast(c[m] * inv);
    }

    // ---- streaming weighted sum (unchanged structure) ----
    vf4 acc[4];
#pragma unroll
    for (int j = 0; j < 4; ++j) {
        acc[j].x = ws[0] * v0[j].x;
        acc[j].y = ws[0] * v0[j].y;
        acc[j].z = ws[0] * v0[j].z;
        acc[j].w = ws[0] * v0[j].w;
    }
#pragma unroll
    for (int m = 1; m < M; ++m) {
        const vf4* __restrict__ p = V + (long long)m * PITCH4 + base;
        vf4 v[4];
#pragma unroll
        for (int j = 0; j < 4; ++j) v[j] = __builtin_nontemporal_load(p + j * 256);
#pragma unroll
        for (int j = 0; j < 4; ++j) {
            acc[j].x = fmaf(ws[m], v[j].x, acc[j].x);
            acc[j].y = fmaf(ws[m], v[j].y, acc[j].y);
            acc[j].z = fmaf(ws[m], v[j].z, acc[j].z);
            acc[j].w = fmaf(ws[m], v[j].w, acc[j].w);
        }
    }
#pragma unroll
    for (int j = 0; j < 4; ++j)
        __builtin_nontemporal_store(acc[j], &out[base + j * 256]);
}

__global__ __launch_bounds__(256) void fused_kernel(
    const vf4* __restrict__ V0,
    const vf4* __restrict__ V1,
    const float* __restrict__ task_emb,
    const float* __restrict__ K_memory,
    vf4* __restrict__ out)
{
    const int b = blockIdx.x;
    if (b < N40 / 1024) {                     // 256 blocks -> V0
        fused_body<N40>(V0, task_emb, K_memory, out, b);
    } else {                                  // 1024 blocks -> V1
        fused_body<N41>(V1, task_emb, K_memory, out + N40, b - N40 / 1024);
    }
}

extern "C" void kernel_launch(void* const* d_in, const int* in_sizes, int n_in,
                              void* d_out, int out_size, void* d_ws, size_t ws_size,
                              hipStream_t stream) {
    const float* task_emb = (const float*)d_in[0];   // [1,1024]
    const float* K_memory = (const float*)d_in[1];   // [16,1024]
    const float* V0       = (const float*)d_in[2];   // [16,1024,1024]
    const float* V1       = (const float*)d_in[3];   // [16,1024,4096]
    float* out = (float*)d_out;                      // [N0 + N1]
    (void)d_ws; (void)ws_size;                       // workspace unused

    const int nblk = (N40 + N41) / 1024;             // 1280 blocks
    fused_kernel<<<nblk, 256, 0, stream>>>(
        (const vf4*)V0, (const vf4*)V1, task_emb, K_memory, (vf4*)out);
}